// Round 12
// baseline (256.072 us; speedup 1.0000x reference)
//
#include <hip/hip_runtime.h>
#include <hip/hip_bf16.h>

#define B_SZ 8192
#define D_SZ 1024   // elements; == bytes in fp8

typedef __attribute__((ext_vector_type(4))) float floatx4;
typedef __attribute__((ext_vector_type(8))) int   int8v;
typedef __attribute__((ext_vector_type(4))) int   int4v;

__device__ __forceinline__ void glds16(const void* g, void* l) {
    __builtin_amdgcn_global_load_lds(
        (const __attribute__((address_space(1))) void*)g,
        (__attribute__((address_space(3))) void*)l, 16, 0, 0);
}

// One wave per row (rows 0..8191 = img, 8192..16383 = txt). 4 rows/block.
// Also zero-inits the output accumulator (stream-ordered before GEMM atomics).
__global__ __launch_bounds__(256) void norm_cast_fp8(
    const float* __restrict__ img, const float* __restrict__ txt,
    unsigned char* __restrict__ imgQ, unsigned char* __restrict__ txtQ,
    float* __restrict__ out)
{
    if (blockIdx.x == 0 && threadIdx.x == 0) *out = 0.0f;

    const int lane = threadIdx.x & 63;
    int w = blockIdx.x * 4 + (threadIdx.x >> 6);
    const float* src; unsigned char* dst;
    if (w < B_SZ) { src = img + (size_t)w * D_SZ; dst = imgQ + (size_t)w * D_SZ; }
    else { w -= B_SZ; src = txt + (size_t)w * D_SZ; dst = txtQ + (size_t)w * D_SZ; }

    float4 v[4];
    float ss = 0.0f;
    #pragma unroll
    for (int i = 0; i < 4; ++i) {
        v[i] = ((const float4*)src)[lane + 64 * i];
        ss += v[i].x*v[i].x + v[i].y*v[i].y + v[i].z*v[i].z + v[i].w*v[i].w;
    }
    #pragma unroll
    for (int off = 1; off < 64; off <<= 1) ss += __shfl_xor(ss, off, 64);
    const float scale = 1.0f / fmaxf(sqrtf(ss), 1e-12f);

    #pragma unroll
    for (int i = 0; i < 4; ++i) {
        int packed = 0;
        packed = __builtin_amdgcn_cvt_pk_fp8_f32(v[i].x * scale, v[i].y * scale, packed, false);
        packed = __builtin_amdgcn_cvt_pk_fp8_f32(v[i].z * scale, v[i].w * scale, packed, true);
        ((int*)dst)[lane + 64 * i] = packed;
    }
}

// R21: A-operands DIRECT FROM GLOBAL (L2/L1), LDS for B only.
// R20's accounting: LDS pipe ~49 us is the largest (reads 64 b128 +
// writes ~1150 cyc per block-iter x 128/CU); half the reads are A-frags
// whose LDS round-trip serves only 2 waves each. Each lane's af fragment
// is two NATURAL 16-B granules of A: bytes row*1024 + kk*128 + quad*16
// and +64 — exactly the granules the R16 LDS path retrieves (= quad,
// quad+4), so loading them directly is BIT-IDENTICAL numerics, matches
// B's K-order, and needs no swizzle.
//   - LDS reads halve (bfr only) -> LDS busy ~28 us
//   - As deleted: LDS 48.5 -> 32.5 KB -> 4 blocks/CU (16 waves)
//   - back to the simple ONE-barrier loop (no A-commit, no BAR2)
//   - L2: 4096 blk x 8 iters x 32 KB ~ 1 GB (~15 TB/s < 34.5 ceiling);
//     16-KB A-window L1-resident, waves 0/2 share rows -> L1 hits.
// Regs: acc 64 (AGPR) + arch {bfr 32, af 8, addr ~20} -> unified ~125;
// __launch_bounds__(256,4) caps at 128 (4 waves/SIMD). Canaries:
// WRITE_SIZE (spill), SQ_LDS_BANK_CONFLICT (must stay 0).
// Bs path + epilogue VERBATIM R16/R20 (proven clean / absmax 0).
__global__ __launch_bounds__(256, 4) void siglip_gemm_loss_fp8(
    const unsigned char* __restrict__ A,   // imgQ [B,D] e4m3
    const unsigned char* __restrict__ Bt,  // txtQ [B,D] e4m3
    const float* __restrict__ tp, const float* __restrict__ bp,
    float* __restrict__ out)
{
    // Bs: double buf [buf][lo/hi][128 rows x 64 B] = 32 KB. No As.
    __shared__ __align__(16) unsigned char Bs[2 * 16384];

    const int tid  = threadIdx.x;
    const int lane = tid & 63;
    const int wave = tid >> 6;
    const int wm = wave & 1, wn = wave >> 1;
    const int bi = blockIdx.x * 128;
    const int bj = blockIdx.y * 128;
    const int quad = lane >> 4;   // 0..3
    const int l16  = lane & 15;

    floatx4 acc[4][4];
    #pragma unroll
    for (int i = 0; i < 4; ++i)
        #pragma unroll
        for (int j = 0; j < 4; ++j)
            acc[i][j] = (floatx4){0.f, 0.f, 0.f, 0.f};

    // B staging (verbatim R16): slot s -> row = s>>2, phys p = s&3,
    // global granule g = p ^ ((row>>1)&3). lo = K-bytes g*16, hi = 64+g*16.
    const int s0 = tid, s1 = tid + 256;
    const int r0 = s0 >> 2, g0 = (s0 & 3) ^ ((r0 >> 1) & 3);
    const int r1 = s1 >> 2, g1 = (s1 & 3) ^ ((r1 >> 1) & 3);
    const unsigned offB0 = (unsigned)(bj + r0) * D_SZ + (unsigned)g0 * 16;
    const unsigned offB1 = (unsigned)(bj + r1) * D_SZ + (unsigned)g1 * 16;

    auto stageB = [&](int k0, int buf) {
        const int d = buf * 16384;
        glds16(Bt + offB0 + k0,      Bs + d + s0 * 16);
        glds16(Bt + offB0 + k0 + 64, Bs + d + 8192 + s0 * 16);
        glds16(Bt + offB1 + k0,      Bs + d + s1 * 16);
        glds16(Bt + offB1 + k0 + 64, Bs + d + 8192 + s1 * 16);
    };

    // B fragment reads (verbatim R16): pos = quad ^ sw -> granule quad.
    const int sw  = (l16 >> 1) & 3;
    const int pos = quad ^ sw;
    const unsigned b_off = (unsigned)((wn * 64 + l16) * 64 + pos * 16);

    // A fragment source (direct): row = bi + wm*64 + mt*16 + l16;
    // granules quad (lo) and quad+4 (hi) of K-window kk.
    const unsigned aRow = (unsigned)(bi + wm * 64 + l16) * D_SZ
                        + (unsigned)quad * 16;

    stageB(0, 0);

    for (int kk = 0; kk < D_SZ / 128; ++kk) {
        const int buf = kk & 1;
        const int d = buf * 16384;
        __syncthreads();   // single barrier: buf tiles visible, buf^1 free

        if (kk + 1 < D_SZ / 128)
            stageB((kk + 1) * 128, buf ^ 1);   // full iteration to land

        int8v bfr[4];
        #pragma unroll
        for (int nt = 0; nt < 4; ++nt) {
            const unsigned char* bp_ = Bs + d + b_off + nt * 1024;
            int4v lo = *(const int4v*)(bp_);
            int4v hi = *(const int4v*)(bp_ + 8192);
            bfr[nt][0]=lo[0]; bfr[nt][1]=lo[1]; bfr[nt][2]=lo[2]; bfr[nt][3]=lo[3];
            bfr[nt][4]=hi[0]; bfr[nt][5]=hi[1]; bfr[nt][6]=hi[2]; bfr[nt][7]=hi[3];
        }

        const unsigned aK = aRow + (unsigned)kk * 128;
        #pragma unroll
        for (int mt = 0; mt < 4; ++mt) {
            const unsigned char* ap_ = A + aK + (unsigned)mt * (16 * D_SZ);
            int4v lo = *(const int4v*)(ap_);        // granule quad
            int4v hi = *(const int4v*)(ap_ + 64);   // granule quad+4
            int8v af;
            af[0]=lo[0]; af[1]=lo[1]; af[2]=lo[2]; af[3]=lo[3];
            af[4]=hi[0]; af[5]=hi[1]; af[6]=hi[2]; af[7]=hi[3];
            #pragma unroll
            for (int nt = 0; nt < 4; ++nt)
                acc[mt][nt] = __builtin_amdgcn_mfma_scale_f32_16x16x128_f8f6f4(
                    af, bfr[nt], acc[mt][nt],
                    0, 0,          // cbsz=fp8, blgp=fp8
                    0, 127,        // scale A: E8M0 127 = 1.0
                    0, 127);       // scale B
        }
    }

    // ---------------- epilogue: series softplus (R16, proven) ----------
    // off-diag: softplus(z) = log1p(e^z), e^z <= ~3e-4
    //   -> x*fma(x, fma(x, 1/3, -1/2), 1), x = e^z.
    const float t    = fminf(__expf(tp[0]), 100.0f);
    const float bias = bp[0];
    const float C3 = 0.33333333f, C2 = -0.5f;
    float lsum = 0.0f;
    #pragma unroll
    for (int mt = 0; mt < 4; ++mt) {
        #pragma unroll
        for (int nt = 0; nt < 4; ++nt) {
            #pragma unroll
            for (int r = 0; r < 4; ++r) {
                float z = fmaf(acc[mt][nt][r], t, bias);
                float x = __expf(z);
                lsum += x * fmaf(x, fmaf(x, C3, C2), 1.0f);
            }
        }
    }
    // diagonal correction (R16-proven): bi==bj, wm==wn, mt==nt,
    // quad == l16>>2, r = l16&3 -> replace series by exact softplus(-z).
    if (bi == bj && wm == wn && quad == (l16 >> 2)) {
        const int r = l16 & 3;
        #pragma unroll
        for (int mt = 0; mt < 4; ++mt) {
            float z = fmaf(acc[mt][mt][r], t, bias);
            float x = __expf(z);
            float series = x * fmaf(x, fmaf(x, C3, C2), 1.0f);
            float exact  = fmaxf(-z, 0.0f) + __logf(1.0f + __expf(-fabsf(z)));
            lsum += exact - series;
        }
    }
    #pragma unroll
    for (int off = 32; off > 0; off >>= 1) lsum += __shfl_down(lsum, off, 64);

    __shared__ float red[4];
    if (lane == 0) red[wave] = lsum;
    __syncthreads();
    if (tid == 0)
        atomicAdd(out, (red[0] + red[1] + red[2] + red[3]) * (1.0f / (float)B_SZ));
}

extern "C" void kernel_launch(void* const* d_in, const int* in_sizes, int n_in,
                              void* d_out, int out_size, void* d_ws, size_t ws_size,
                              hipStream_t stream) {
    const float* img = (const float*)d_in[0];
    const float* txt = (const float*)d_in[1];
    const float* tp  = (const float*)d_in[2];
    const float* bp  = (const float*)d_in[3];
    float* out = (float*)d_out;

    unsigned char* imgQ = (unsigned char*)d_ws;                   // 8 MB
    unsigned char* txtQ = imgQ + (size_t)B_SZ * D_SZ;             // 8 MB

    norm_cast_fp8<<<(2 * B_SZ) / 4, 256, 0, stream>>>(img, txt, imgQ, txtQ, out);
    dim3 grid(B_SZ / 128, B_SZ / 128);
    siglip_gemm_loss_fp8<<<grid, 256, 0, stream>>>(imgQ, txtQ, tp, bp, out);
}